// Round 4
// baseline (155.876 us; speedup 1.0000x reference)
//
#include <hip/hip_runtime.h>
#include <math.h>

#define B_   8
#define CIN  256
#define L_   1024
#define NH_  8
#define DH_  32

typedef __attribute__((ext_vector_type(8))) short short8;
typedef __attribute__((ext_vector_type(4))) short short4v;
typedef __attribute__((ext_vector_type(4))) float f32x4;
typedef __attribute__((ext_vector_type(4))) unsigned int uint4v;
typedef __attribute__((ext_vector_type(2))) unsigned int uint2v;

__device__ inline short f2bf_hu(float f) {       // bf16 half-up, 2 ops
    union { float f; unsigned u; } v; v.f = f;
    return (short)((v.u + 0x8000u) >> 16);
}
__device__ inline float bf2f(short s) {          // bf16 -> fp32, 1 shift
    union { unsigned u; float f; } v; v.u = ((unsigned)(unsigned short)s) << 16;
    return v.f;
}
// pack bf16(a) | bf16(b)<<16 : 2 adds + 1 v_perm
__device__ inline unsigned pkbf2(float a, float b) {
    union { float f; unsigned u; } x, y; x.f = a; y.f = b;
    return __builtin_amdgcn_perm(y.u + 0x8000u, x.u + 0x8000u, 0x07060302u);
}
// async global->LDS, 16B per lane; LDS dest = wave-uniform base + lane*16
__device__ inline void glds16(const void* g, void* l) {
    __builtin_amdgcn_global_load_lds(
        (const __attribute__((address_space(1))) void*)g,
        (__attribute__((address_space(3))) void*)l, 16, 0, 0);
}

// ---------------------------------------------------------------------------
// Weight pre-convert: w_qkv + w_proj fp32 -> bf16 (unchanged).
// ---------------------------------------------------------------------------
__global__ __launch_bounds__(256) void wconv(
    const float* __restrict__ wq, const float* __restrict__ wp,
    short* __restrict__ w2)
{
    const size_t e = ((size_t)blockIdx.x * 256 + threadIdx.x) * 8;
    const float* src = (e < (size_t)768 * 256) ? wq + e : wp + (e - (size_t)768 * 256);
    const float4 a = *(const float4*)src;
    const float4 c = *(const float4*)(src + 4);
    uint4v pk = { pkbf2(a.x, a.y), pkbf2(a.z, a.w),
                  pkbf2(c.x, c.y), pkbf2(c.z, c.w) };
    *(uint4v*)(w2 + e) = pk;
}

// ---------------------------------------------------------------------------
// QKV GEMM (byte-identical to round 1).
// ---------------------------------------------------------------------------
__global__ __launch_bounds__(256) void qkv_gemm(
    const float* __restrict__ x, const short* __restrict__ w2,
    const float* __restrict__ bias, short* __restrict__ qkvT)
{
    __shared__ __align__(16) short Xs[2][64][40];
    __shared__ __align__(16) short Wt[2][128][32];   // linear rows, swizzled content
    const int t = threadIdx.x, lane = t & 63, wv = t >> 6;
    const int n = lane & 15, quad = lane >> 4;
    const int b = blockIdx.z, o0 = blockIdx.y * 128, l0 = blockIdx.x * 64;

    float bias_r[8];
    #pragma unroll
    for (int nf = 0; nf < 8; nf++) bias_r[nf] = bias[o0 + nf * 16 + n];

    f32x4 acc[8];
    #pragma unroll
    for (int nf = 0; nf < 8; nf++) acc[nf] = (f32x4){0.f, 0.f, 0.f, 0.f};

    const int cS = t >> 3, lsS = (t & 7) * 8;       // X stage roles

    const int oA = wv * 32 + (lane >> 2);
    const int cc = (lane & 3) ^ ((oA >> 1) & 3);
    const short* wpA = w2 + (size_t)(o0 + oA) * 256 + cc * 8;
    const short* wpB = wpA + 16 * 256;
    short* const ldsW0 = &Wt[0][0][0] + wv * 1024;
    short* const ldsW1 = &Wt[1][0][0] + wv * 1024;

    auto xwrite = [&](int buf, const float4& a, const float4& c) {
        const float vals[8] = {a.x, a.y, a.z, a.w, c.x, c.y, c.z, c.w};
        #pragma unroll
        for (int k = 0; k < 8; k++) {
            const int ll = lsS + k;
            const int col = (((cS >> 3) ^ (ll & 3)) << 3) | (cS & 7);
            Xs[buf][ll][col] = f2bf_hu(vals[k]);
        }
    };

    const float* xp = &x[(((size_t)b * CIN + cS) << 10) + l0 + lsS];
    float4 xa = *(const float4*)xp, xb = *(const float4*)(xp + 4);
    glds16(wpA, ldsW0);
    glds16(wpB, ldsW0 + 512);
    xwrite(0, xa, xb);
    xp += (size_t)32 << 10;
    xa = *(const float4*)xp; xb = *(const float4*)(xp + 4);

    const int wsw = (quad ^ ((n >> 1) & 3)) * 8;
    const int arow = wv * 16 + n;
    const int xsw = (quad ^ (arow & 3)) * 8;

    #pragma unroll
    for (int it = 0; it < 8; it++) {
        const int cur = it & 1;
        __syncthreads();
        if (it < 7) {
            short* ldsn = (cur ? ldsW0 : ldsW1);
            glds16(wpA + (it + 1) * 32, ldsn);
            glds16(wpB + (it + 1) * 32, ldsn + 512);
        }
        const short8 af = *(const short8*)&Xs[cur][arow][xsw];
        #pragma unroll
        for (int nf = 0; nf < 8; nf++) {
            const short8 bf = *(const short8*)&Wt[cur][nf * 16 + n][wsw];
            acc[nf] = __builtin_amdgcn_mfma_f32_16x16x32_bf16(af, bf, acc[nf], 0, 0, 0);
        }
        if (it < 7) {
            xwrite(cur ^ 1, xa, xb);
            if (it < 6) {
                xp += (size_t)32 << 10;
                xa = *(const float4*)xp; xb = *(const float4*)(xp + 4);
            }
        }
    }

    #pragma unroll
    for (int reg = 0; reg < 4; reg++) {
        const size_t l = l0 + wv * 16 + quad * 4 + reg;
        short* row = qkvT + (((size_t)b << 10) + l) * 768 + o0 + n;
        #pragma unroll
        for (int nf = 0; nf < 8; nf++)
            row[nf * 16] = f2bf_hu(acc[nf][reg] + bias_r[nf]);
    }
}

// ---------------------------------------------------------------------------
// Proj GEMM with fused split-j combine (byte-identical to round 1).
// ---------------------------------------------------------------------------
__global__ __launch_bounds__(256) void proj_gemm(
    const short* __restrict__ partO, const float* __restrict__ partD,
    const short* __restrict__ w2, const float* __restrict__ bias,
    const float* __restrict__ resid, float* __restrict__ out)
{
    __shared__ __align__(16) short Xs[2][64][40];
    __shared__ __align__(16) short Wt[2][64][32];
    const int t = threadIdx.x, lane = t & 63, wv = t >> 6;
    const int n = lane & 15, quad = lane >> 4;
    const int b = blockIdx.z, o0 = blockIdx.y * 64, l0 = blockIdx.x * 64;

    float bias_r[4];
    #pragma unroll
    for (int reg = 0; reg < 4; reg++) bias_r[reg] = bias[o0 + wv * 16 + quad * 4 + reg];

    f32x4 acc[4];
    #pragma unroll
    for (int nf = 0; nf < 4; nf++) acc[nf] = (f32x4){0.f, 0.f, 0.f, 0.f};

    // combine-stage roles: one l-row, 8 c's per thread
    const int l = t >> 2, cs = (t & 3) * 8;
    const size_t li = ((size_t)b << 10) + l0 + l;
    const short* p0 = &partO[(0 * (size_t)B_ * L_ + li) * CIN + cs];
    const short* p1 = &partO[(1 * (size_t)B_ * L_ + li) * CIN + cs];
    const float* pd0 = &partD[(0 * (size_t)B_ * L_ + li) * NH_];
    const float* pd1 = &partD[(1 * (size_t)B_ * L_ + li) * NH_];

    const int og = wv * 16 + (lane >> 2);
    const int ccg = (lane & 3) ^ ((og >> 1) & 3);
    const short* wp = w2 + (size_t)(o0 + og) * 256 + ccg * 8;
    short* const ldsW0 = &Wt[0][0][0] + wv * 512;
    short* const ldsW1 = &Wt[1][0][0] + wv * 512;

    short8 s0, s1;
    float d0, d1;
    auto combine_write = [&](int buf) {
        const float inv = 1.f / (d0 + d1);
        float v[8];
        #pragma unroll
        for (int e = 0; e < 8; e++) v[e] = (bf2f(s0[e]) + bf2f(s1[e])) * inv;
        uint4v pw = { pkbf2(v[0], v[1]), pkbf2(v[2], v[3]),
                      pkbf2(v[4], v[5]), pkbf2(v[6], v[7]) };
        *(uint4v*)&Xs[buf][l][cs] = pw;
    };

    // prologue
    s0 = *(const short8*)p0; s1 = *(const short8*)p1;
    d0 = pd0[0]; d1 = pd1[0];
    glds16(wp, ldsW0);
    combine_write(0);
    p0 += 32; p1 += 32;
    s0 = *(const short8*)p0; s1 = *(const short8*)p1;
    d0 = pd0[1]; d1 = pd1[1];

    const int wsw = (quad ^ ((n >> 1) & 3)) * 8;
    #pragma unroll
    for (int it = 0; it < 8; it++) {
        const int cur = it & 1;
        __syncthreads();
        if (it < 7) glds16(wp + (it + 1) * 32, cur ? ldsW0 : ldsW1);
        const short8 af = *(const short8*)&Wt[cur][wv * 16 + n][wsw];
        #pragma unroll
        for (int nf = 0; nf < 4; nf++) {
            const short8 bf = *(const short8*)&Xs[cur][nf * 16 + n][quad * 8];
            acc[nf] = __builtin_amdgcn_mfma_f32_16x16x32_bf16(af, bf, acc[nf], 0, 0, 0);
        }
        if (it < 7) {
            combine_write(cur ^ 1);
            if (it < 6) {
                p0 += 32; p1 += 32;
                s0 = *(const short8*)p0; s1 = *(const short8*)p1;
                d0 = pd0[it + 2]; d1 = pd1[it + 2];
            }
        }
    }

    #pragma unroll
    for (int reg = 0; reg < 4; reg++) {
        const int o = o0 + wv * 16 + quad * 4 + reg;
        #pragma unroll
        for (int nf = 0; nf < 4; nf++) {
            const size_t off = (((size_t)b * CIN + o) << 10) + l0 + nf * 16 + n;
            out[off] = acc[nf][reg] + bias_r[reg] + resid[off];
        }
    }
}

// ---------------------------------------------------------------------------
// Flash attention (byte-identical to round 1: j-split x2, Q-tile 128).
// ---------------------------------------------------------------------------
__global__ __launch_bounds__(256) void attn_mfma(
    const short* __restrict__ qkvT, short* __restrict__ partO,
    float* __restrict__ partD)
{
    __shared__ short Vt[2][32][80];                // col ^= ((dv>>2)&7)<<3
    __shared__ __align__(16) short Ss[128][88];    // [i][j] bf16 P (wave-private rows)

    const int t = threadIdx.x, lane = t & 63, wv = t >> 6;
    const int n = lane & 15, quad = lane >> 4;
    const int id = blockIdx.x;
    const int bh = id & 63;                        // same-(b,h) -> same XCD
    const int b = bh >> 3, h = bh & 7;
    const int i0 = ((id >> 6) & 7) * 128;
    const int s  = id >> 9;                        // j-split 0/1

    const short* base = qkvT + ((size_t)b << 10) * 768;

    short8 qa[2];
    #pragma unroll
    for (int a = 0; a < 2; a++)
        qa[a] = *(const short8*)&base[(size_t)(i0 + wv * 32 + a * 16 + n) * 768
                                      + h * DH_ + quad * 8];

    short8 vf2;   // ones-column B-frag (denominator)
    {
        const short one = (n == 0) ? (short)0x3F80 : (short)0;
        #pragma unroll
        for (int u = 0; u < 8; u++) vf2[u] = one;
    }

    f32x4 o_acc[2][3];
    #pragma unroll
    for (int a = 0; a < 2; a++)
        #pragma unroll
        for (int nf = 0; nf < 3; nf++) o_acc[a][nf] = (f32x4){0.f, 0.f, 0.f, 0.f};

    const float K1 = 0.25503510f;    // (1/sqrt(32)) * log2(e)
    const float K2 = 11.54156036f;   // 8 * log2(e)
    const int TSTRIDE = 64 * 768;    // shorts per j-tile

    const size_t soff = (size_t)s * 8 * TSTRIDE;   // this block's j-half
    const short* kp0 = base + 256 + h * DH_ + (size_t)n * 768 + quad * 8 + soff;
    const short* kp1 = kp0 + 16 * 768;
    const short* kp2 = kp0 + 32 * 768;
    const short* kp3 = kp0 + 48 * 768;
    const int jS = t >> 3, dsS = (t & 7) * 4;
    const short* vp0 = base + 512 + h * DH_ + (size_t)jS * 768 + dsS + soff;
    const short* vp1 = vp0 + 32 * 768;

    const int vmsk = ((dsS >> 2) & 7) << 3;
    const int vwo0 = dsS * 80 + (jS ^ vmsk);
    const int vwo1 = dsS * 80 + ((jS + 32) ^ vmsk);
    short* const vtb0 = &Vt[0][0][0];
    short* const vtb1 = &Vt[1][0][0];
    short* const ssw  = &Ss[wv * 32 + n][quad * 4];        // + a*16*88 + f*16
    const short* const ssr = &Ss[wv * 32 + n][quad * 8];   // + a*16*88 + kk*32
    int vro[2][2];
    #pragma unroll
    for (int nf = 0; nf < 2; nf++) {
        const int dv = nf * 16 + n;
        const int msk = ((dv >> 2) & 7) << 3;
        #pragma unroll
        for (int kk = 0; kk < 2; kk++)
            vro[kk][nf] = dv * 80 + ((kk * 32 + quad * 8) ^ msk);
    }

    short8 kfA[4], kfB[4];

    auto stageV = [&](short* vtb) {
        const short4v a = *(const short4v*)vp0; vp0 += TSTRIDE;
        const short4v c = *(const short4v*)vp1; vp1 += TSTRIDE;
        #pragma unroll
        for (int u = 0; u < 4; u++) {
            vtb[vwo0 + u * 80] = a[u];
            vtb[vwo1 + u * 80] = c[u];
        }
    };
    auto loadK = [&](short8* kf) {
        kf[0] = *(const short8*)kp0; kp0 += TSTRIDE;
        kf[1] = *(const short8*)kp1; kp1 += TSTRIDE;
        kf[2] = *(const short8*)kp2; kp2 += TSTRIDE;
        kf[3] = *(const short8*)kp3; kp3 += TSTRIDE;
    };
    auto tile = [&](const short8* kf, const short* vtb) {
        #pragma unroll
        for (int f = 0; f < 4; f++) {
            #pragma unroll
            for (int a = 0; a < 2; a++) {
                f32x4 z = {0.f, 0.f, 0.f, 0.f};
                const f32x4 sv = __builtin_amdgcn_mfma_f32_16x16x32_bf16(kf[f], qa[a], z, 0, 0, 0);
                const float p0 = __builtin_amdgcn_exp2f(fmaf(sv[0], K1, -K2));
                const float p1 = __builtin_amdgcn_exp2f(fmaf(sv[1], K1, -K2));
                const float p2 = __builtin_amdgcn_exp2f(fmaf(sv[2], K1, -K2));
                const float p3 = __builtin_amdgcn_exp2f(fmaf(sv[3], K1, -K2));
                uint2v pk = { pkbf2(p0, p1), pkbf2(p2, p3) };
                *(uint2v*)(ssw + a * 16 * 88 + f * 16) = pk;
            }
        }
        // wave-private Ss rows: in-wave DS ordering, no barrier
        #pragma unroll
        for (int kk = 0; kk < 2; kk++) {
            short8 pf[2];
            #pragma unroll
            for (int a = 0; a < 2; a++)
                pf[a] = *(const short8*)(ssr + a * 16 * 88 + kk * 32);
            #pragma unroll
            for (int nf = 0; nf < 2; nf++) {
                const short8 vf = *(const short8*)(vtb + vro[kk][nf]);
                #pragma unroll
                for (int a = 0; a < 2; a++)
                    o_acc[a][nf] = __builtin_amdgcn_mfma_f32_16x16x32_bf16(pf[a], vf, o_acc[a][nf], 0, 0, 0);
            }
            #pragma unroll
            for (int a = 0; a < 2; a++)
                o_acc[a][2] = __builtin_amdgcn_mfma_f32_16x16x32_bf16(pf[a], vf2, o_acc[a][2], 0, 0, 0);
        }
    };

    stageV(vtb0);
    loadK(kfA);

    for (int itp = 0; itp < 4; itp++) {     // 8 j-tiles (this block's half)
        __syncthreads();
        stageV(vtb1);
        loadK(kfB);
        tile(kfA, vtb0);
        __syncthreads();
        if (itp < 3) { stageV(vtb0); loadK(kfA); }
        tile(kfB, vtb1);
    }

    // ---- epilogue: bf16 partial stores, fp32 denominators ----
    #pragma unroll
    for (int a = 0; a < 2; a++) {
        #pragma unroll
        for (int r = 0; r < 4; r++) {
            const int il = i0 + wv * 32 + a * 16 + quad * 4 + r;
            short* po = partO + (((size_t)s * B_ + b) * L_ + il) * CIN + h * DH_;
            po[n]      = f2bf_hu(o_acc[a][0][r]);
            po[16 + n] = f2bf_hu(o_acc[a][1][r]);
        }
    }
    if (n == 0) {
        #pragma unroll
        for (int a = 0; a < 2; a++)
            #pragma unroll
            for (int r = 0; r < 4; r++) {
                const int il = i0 + wv * 32 + a * 16 + quad * 4 + r;
                partD[(((size_t)s * B_ + b) * L_ + il) * NH_ + h] = o_acc[a][2][r];
            }
    }
}

// ---------------------------------------------------------------------------
// ATTRIBUTION ROUND 2: every kernel dispatched TWICE (all idempotent; output
// bytes identical to round 1, absmax must stay 0.03125).
//   dur(R4) - dur(R1=111.88) = t_wconv + t_qkv + t_attn + t_proj + 4*gap
// Combined with R3 (t_attn + gap = 22.41) this splits kernel time from
// fixed overhead and decides GEMM-rewrite vs cooperative-fusion for R5.
// ---------------------------------------------------------------------------
extern "C" void kernel_launch(void* const* d_in, const int* in_sizes, int n_in,
                              void* d_out, int out_size, void* d_ws, size_t ws_size,
                              hipStream_t stream) {
    const float* x      = (const float*)d_in[0];
    const float* w_qkv  = (const float*)d_in[1];
    const float* b_qkv  = (const float*)d_in[2];
    const float* w_proj = (const float*)d_in[3];
    const float* b_proj = (const float*)d_in[4];
    float* out = (float*)d_out;

    short* qkvT  = (short*)d_ws;                                // 12 MB bf16 [b][l][768]
    short* partO = qkvT + (size_t)B_ * L_ * 768;                // 8.4 MB bf16 [2][b][l][256]
    float* partD = (float*)(partO + (size_t)2 * B_ * L_ * CIN); // 0.5 MB fp32 [2][b][l][8]
    short* w2    = (short*)(partD + (size_t)2 * B_ * L_ * NH_); // 0.5 MB bf16 weights

    wconv<<<dim3(128), 256, 0, stream>>>(w_qkv, w_proj, w2);
    wconv<<<dim3(128), 256, 0, stream>>>(w_qkv, w_proj, w2);             // dup (probe)
    qkv_gemm<<<dim3(16, 6, B_), 256, 0, stream>>>(x, w2, b_qkv, qkvT);
    qkv_gemm<<<dim3(16, 6, B_), 256, 0, stream>>>(x, w2, b_qkv, qkvT);   // dup (probe)
    attn_mfma<<<dim3(1024), 256, 0, stream>>>(qkvT, partO, partD);
    attn_mfma<<<dim3(1024), 256, 0, stream>>>(qkvT, partO, partD);       // dup (probe)
    proj_gemm<<<dim3(16, 4, B_), 256, 0, stream>>>(partO, partD, w2 + (size_t)768 * 256,
                                                   b_proj, x, out);
    proj_gemm<<<dim3(16, 4, B_), 256, 0, stream>>>(partO, partD, w2 + (size_t)768 * 256,
                                                   b_proj, x, out);      // dup (probe)
}

// Round 5
// 109.652 us; speedup vs baseline: 1.4215x; 1.4215x over previous
//
#include <hip/hip_runtime.h>
#include <math.h>

#define B_   8
#define CIN  256
#define L_   1024
#define NH_  8
#define DH_  32

typedef __attribute__((ext_vector_type(8))) short short8;
typedef __attribute__((ext_vector_type(4))) short short4v;
typedef __attribute__((ext_vector_type(4))) float f32x4;
typedef __attribute__((ext_vector_type(4))) unsigned int uint4v;
typedef __attribute__((ext_vector_type(2))) unsigned int uint2v;

__device__ inline short f2bf_hu(float f) {       // bf16 half-up, 2 ops
    union { float f; unsigned u; } v; v.f = f;
    return (short)((v.u + 0x8000u) >> 16);
}
__device__ inline float bf2f(short s) {          // bf16 -> fp32, 1 shift
    union { unsigned u; float f; } v; v.u = ((unsigned)(unsigned short)s) << 16;
    return v.f;
}
// pack bf16(a) | bf16(b)<<16 : 2 adds + 1 v_perm
__device__ inline unsigned pkbf2(float a, float b) {
    union { float f; unsigned u; } x, y; x.f = a; y.f = b;
    return __builtin_amdgcn_perm(y.u + 0x8000u, x.u + 0x8000u, 0x07060302u);
}
// async global->LDS, 16B per lane; LDS dest = wave-uniform base + lane*16
__device__ inline void glds16(const void* g, void* l) {
    __builtin_amdgcn_global_load_lds(
        (const __attribute__((address_space(1))) void*)g,
        (__attribute__((address_space(3))) void*)l, 16, 0, 0);
}

// ---------------------------------------------------------------------------
// Weight pre-convert: w_qkv + w_proj fp32 -> bf16 (byte-identical to R1).
// ---------------------------------------------------------------------------
__global__ __launch_bounds__(256) void wconv(
    const float* __restrict__ wq, const float* __restrict__ wp,
    short* __restrict__ w2)
{
    const size_t e = ((size_t)blockIdx.x * 256 + threadIdx.x) * 8;
    const float* src = (e < (size_t)768 * 256) ? wq + e : wp + (e - (size_t)768 * 256);
    const float4 a = *(const float4*)src;
    const float4 c = *(const float4*)(src + 4);
    uint4v pk = { pkbf2(a.x, a.y), pkbf2(a.z, a.w),
                  pkbf2(c.x, c.y), pkbf2(c.z, c.w) };
    *(uint4v*)(w2 + e) = pk;
}

// ---------------------------------------------------------------------------
// QKV GEMM — identical math/staging to R1; ONLY the epilogue store layout
// changed: head-grouped qkv3[t][b][h][l][32] (t=0 Q, 1 K, 2 V) so that
// attention's K/V/Q loads are fully coalesced (were 1536B-stride gathers).
// ---------------------------------------------------------------------------
__global__ __launch_bounds__(256) void qkv_gemm(
    const float* __restrict__ x, const short* __restrict__ w2,
    const float* __restrict__ bias, short* __restrict__ qkv3)
{
    __shared__ __align__(16) short Xs[2][64][40];
    __shared__ __align__(16) short Wt[2][128][32];   // linear rows, swizzled content
    const int t = threadIdx.x, lane = t & 63, wv = t >> 6;
    const int n = lane & 15, quad = lane >> 4;
    const int b = blockIdx.z, o0 = blockIdx.y * 128, l0 = blockIdx.x * 64;

    float bias_r[8];
    #pragma unroll
    for (int nf = 0; nf < 8; nf++) bias_r[nf] = bias[o0 + nf * 16 + n];

    f32x4 acc[8];
    #pragma unroll
    for (int nf = 0; nf < 8; nf++) acc[nf] = (f32x4){0.f, 0.f, 0.f, 0.f};

    const int cS = t >> 3, lsS = (t & 7) * 8;       // X stage roles

    const int oA = wv * 32 + (lane >> 2);
    const int cc = (lane & 3) ^ ((oA >> 1) & 3);
    const short* wpA = w2 + (size_t)(o0 + oA) * 256 + cc * 8;
    const short* wpB = wpA + 16 * 256;
    short* const ldsW0 = &Wt[0][0][0] + wv * 1024;
    short* const ldsW1 = &Wt[1][0][0] + wv * 1024;

    auto xwrite = [&](int buf, const float4& a, const float4& c) {
        const float vals[8] = {a.x, a.y, a.z, a.w, c.x, c.y, c.z, c.w};
        #pragma unroll
        for (int k = 0; k < 8; k++) {
            const int ll = lsS + k;
            const int col = (((cS >> 3) ^ (ll & 3)) << 3) | (cS & 7);
            Xs[buf][ll][col] = f2bf_hu(vals[k]);
        }
    };

    const float* xp = &x[(((size_t)b * CIN + cS) << 10) + l0 + lsS];
    float4 xa = *(const float4*)xp, xb = *(const float4*)(xp + 4);
    glds16(wpA, ldsW0);
    glds16(wpB, ldsW0 + 512);
    xwrite(0, xa, xb);
    xp += (size_t)32 << 10;
    xa = *(const float4*)xp; xb = *(const float4*)(xp + 4);

    const int wsw = (quad ^ ((n >> 1) & 3)) * 8;
    const int arow = wv * 16 + n;
    const int xsw = (quad ^ (arow & 3)) * 8;

    #pragma unroll
    for (int it = 0; it < 8; it++) {
        const int cur = it & 1;
        __syncthreads();
        if (it < 7) {
            short* ldsn = (cur ? ldsW0 : ldsW1);
            glds16(wpA + (it + 1) * 32, ldsn);
            glds16(wpB + (it + 1) * 32, ldsn + 512);
        }
        const short8 af = *(const short8*)&Xs[cur][arow][xsw];
        #pragma unroll
        for (int nf = 0; nf < 8; nf++) {
            const short8 bf = *(const short8*)&Wt[cur][nf * 16 + n][wsw];
            acc[nf] = __builtin_amdgcn_mfma_f32_16x16x32_bf16(af, bf, acc[nf], 0, 0, 0);
        }
        if (it < 7) {
            xwrite(cur ^ 1, xa, xb);
            if (it < 6) {
                xp += (size_t)32 << 10;
                xa = *(const float4*)xp; xb = *(const float4*)(xp + 4);
            }
        }
    }

    // epilogue: head-grouped store. o = o0 + nf*16 + n;
    // plane t = o>>8, head h = (o>>5)&7, dh = (o&31) = (nf&1)*16 + n.
    #pragma unroll
    for (int reg = 0; reg < 4; reg++) {
        const size_t l = l0 + wv * 16 + quad * 4 + reg;
        #pragma unroll
        for (int nf = 0; nf < 8; nf++) {
            const int o = o0 + nf * 16;
            const int tpl = o >> 8, hh = (o >> 5) & 7, dh0 = o & 31;
            short* dst = qkv3 + (((size_t)(tpl * 64 + b * 8 + hh)) << 15)
                              + l * 32 + dh0 + n;
            *dst = f2bf_hu(acc[nf][reg] + bias_r[nf]);
        }
    }
}

// ---------------------------------------------------------------------------
// Proj GEMM with fused split-j combine (byte-identical to R1).
// ---------------------------------------------------------------------------
__global__ __launch_bounds__(256) void proj_gemm(
    const short* __restrict__ partO, const float* __restrict__ partD,
    const short* __restrict__ w2, const float* __restrict__ bias,
    const float* __restrict__ resid, float* __restrict__ out)
{
    __shared__ __align__(16) short Xs[2][64][40];
    __shared__ __align__(16) short Wt[2][64][32];
    const int t = threadIdx.x, lane = t & 63, wv = t >> 6;
    const int n = lane & 15, quad = lane >> 4;
    const int b = blockIdx.z, o0 = blockIdx.y * 64, l0 = blockIdx.x * 64;

    float bias_r[4];
    #pragma unroll
    for (int reg = 0; reg < 4; reg++) bias_r[reg] = bias[o0 + wv * 16 + quad * 4 + reg];

    f32x4 acc[4];
    #pragma unroll
    for (int nf = 0; nf < 4; nf++) acc[nf] = (f32x4){0.f, 0.f, 0.f, 0.f};

    // combine-stage roles: one l-row, 8 c's per thread
    const int l = t >> 2, cs = (t & 3) * 8;
    const size_t li = ((size_t)b << 10) + l0 + l;
    const short* p0 = &partO[(0 * (size_t)B_ * L_ + li) * CIN + cs];
    const short* p1 = &partO[(1 * (size_t)B_ * L_ + li) * CIN + cs];
    const float* pd0 = &partD[(0 * (size_t)B_ * L_ + li) * NH_];
    const float* pd1 = &partD[(1 * (size_t)B_ * L_ + li) * NH_];

    const int og = wv * 16 + (lane >> 2);
    const int ccg = (lane & 3) ^ ((og >> 1) & 3);
    const short* wp = w2 + (size_t)(o0 + og) * 256 + ccg * 8;
    short* const ldsW0 = &Wt[0][0][0] + wv * 512;
    short* const ldsW1 = &Wt[1][0][0] + wv * 512;

    short8 s0, s1;
    float d0, d1;
    auto combine_write = [&](int buf) {
        const float inv = 1.f / (d0 + d1);
        float v[8];
        #pragma unroll
        for (int e = 0; e < 8; e++) v[e] = (bf2f(s0[e]) + bf2f(s1[e])) * inv;
        uint4v pw = { pkbf2(v[0], v[1]), pkbf2(v[2], v[3]),
                      pkbf2(v[4], v[5]), pkbf2(v[6], v[7]) };
        *(uint4v*)&Xs[buf][l][cs] = pw;
    };

    // prologue
    s0 = *(const short8*)p0; s1 = *(const short8*)p1;
    d0 = pd0[0]; d1 = pd1[0];
    glds16(wp, ldsW0);
    combine_write(0);
    p0 += 32; p1 += 32;
    s0 = *(const short8*)p0; s1 = *(const short8*)p1;
    d0 = pd0[1]; d1 = pd1[1];

    const int wsw = (quad ^ ((n >> 1) & 3)) * 8;
    #pragma unroll
    for (int it = 0; it < 8; it++) {
        const int cur = it & 1;
        __syncthreads();
        if (it < 7) glds16(wp + (it + 1) * 32, cur ? ldsW0 : ldsW1);
        const short8 af = *(const short8*)&Wt[cur][wv * 16 + n][wsw];
        #pragma unroll
        for (int nf = 0; nf < 4; nf++) {
            const short8 bf = *(const short8*)&Xs[cur][nf * 16 + n][quad * 8];
            acc[nf] = __builtin_amdgcn_mfma_f32_16x16x32_bf16(af, bf, acc[nf], 0, 0, 0);
        }
        if (it < 7) {
            combine_write(cur ^ 1);
            if (it < 6) {
                p0 += 32; p1 += 32;
                s0 = *(const short8*)p0; s1 = *(const short8*)p1;
                d0 = pd0[it + 2]; d1 = pd1[it + 2];
            }
        }
    }

    #pragma unroll
    for (int reg = 0; reg < 4; reg++) {
        const int o = o0 + wv * 16 + quad * 4 + reg;
        #pragma unroll
        for (int nf = 0; nf < 4; nf++) {
            const size_t off = (((size_t)b * CIN + o) << 10) + l0 + nf * 16 + n;
            out[off] = acc[nf][reg] + bias_r[reg] + resid[off];
        }
    }
}

// ---------------------------------------------------------------------------
// Flash attention — structure byte-identical to R1 (j-split x2, Q-tile 128,
// V dbuf LDS, wave-private Ss). ONLY the global addressing changed to the
// head-grouped qkv3 layout: loadK = 1KB contiguous/wave (was 64-line gather),
// stageV = 512B contiguous/wave (was gather), Q prologue coalesced.
// ---------------------------------------------------------------------------
__global__ __launch_bounds__(256) void attn_mfma(
    const short* __restrict__ qkv3, short* __restrict__ partO,
    float* __restrict__ partD)
{
    __shared__ short Vt[2][32][80];                // col ^= ((dv>>2)&7)<<3
    __shared__ __align__(16) short Ss[128][88];    // [i][j] bf16 P (wave-private rows)

    const int t = threadIdx.x, lane = t & 63, wv = t >> 6;
    const int n = lane & 15, quad = lane >> 4;
    const int id = blockIdx.x;
    const int bh = id & 63;                        // same-(b,h) -> same XCD
    const int b = bh >> 3, h = bh & 7;
    const int i0 = ((id >> 6) & 7) * 128;
    const int s  = id >> 9;                        // j-split 0/1

    // head-grouped planes: Q at 0, K at +2M shorts, V at +4M shorts
    const short* qbase = qkv3 + ((size_t)(b * 8 + h) << 15);
    const short* kbase = qbase + ((size_t)64 << 15);
    const short* vbase = qbase + ((size_t)128 << 15);

    short8 qa[2];
    #pragma unroll
    for (int a = 0; a < 2; a++)
        qa[a] = *(const short8*)&qbase[(size_t)(i0 + wv * 32 + a * 16 + n) * 32
                                       + quad * 8];

    short8 vf2;   // ones-column B-frag (denominator)
    {
        const short one = (n == 0) ? (short)0x3F80 : (short)0;
        #pragma unroll
        for (int u = 0; u < 8; u++) vf2[u] = one;
    }

    f32x4 o_acc[2][3];
    #pragma unroll
    for (int a = 0; a < 2; a++)
        #pragma unroll
        for (int nf = 0; nf < 3; nf++) o_acc[a][nf] = (f32x4){0.f, 0.f, 0.f, 0.f};

    const float K1 = 0.25503510f;    // (1/sqrt(32)) * log2(e)
    const float K2 = 11.54156036f;   // 8 * log2(e)
    const int TSTRIDE = 64 * 32;     // shorts per j-tile (head-grouped)

    const size_t soff = (size_t)s * 8 * TSTRIDE;   // this block's j-half
    const short* kp0 = kbase + soff + (size_t)n * 32 + quad * 8;
    const short* kp1 = kp0 + 16 * 32;
    const short* kp2 = kp0 + 32 * 32;
    const short* kp3 = kp0 + 48 * 32;
    const int jS = t >> 3, dsS = (t & 7) * 4;
    const short* vp0 = vbase + soff + (size_t)jS * 32 + dsS;
    const short* vp1 = vp0 + 32 * 32;

    const int vmsk = ((dsS >> 2) & 7) << 3;
    const int vwo0 = dsS * 80 + (jS ^ vmsk);
    const int vwo1 = dsS * 80 + ((jS + 32) ^ vmsk);
    short* const vtb0 = &Vt[0][0][0];
    short* const vtb1 = &Vt[1][0][0];
    short* const ssw  = &Ss[wv * 32 + n][quad * 4];        // + a*16*88 + f*16
    const short* const ssr = &Ss[wv * 32 + n][quad * 8];   // + a*16*88 + kk*32
    int vro[2][2];
    #pragma unroll
    for (int nf = 0; nf < 2; nf++) {
        const int dv = nf * 16 + n;
        const int msk = ((dv >> 2) & 7) << 3;
        #pragma unroll
        for (int kk = 0; kk < 2; kk++)
            vro[kk][nf] = dv * 80 + ((kk * 32 + quad * 8) ^ msk);
    }

    short8 kfA[4], kfB[4];

    auto stageV = [&](short* vtb) {
        const short4v a = *(const short4v*)vp0; vp0 += TSTRIDE;
        const short4v c = *(const short4v*)vp1; vp1 += TSTRIDE;
        #pragma unroll
        for (int u = 0; u < 4; u++) {
            vtb[vwo0 + u * 80] = a[u];
            vtb[vwo1 + u * 80] = c[u];
        }
    };
    auto loadK = [&](short8* kf) {
        kf[0] = *(const short8*)kp0; kp0 += TSTRIDE;
        kf[1] = *(const short8*)kp1; kp1 += TSTRIDE;
        kf[2] = *(const short8*)kp2; kp2 += TSTRIDE;
        kf[3] = *(const short8*)kp3; kp3 += TSTRIDE;
    };
    auto tile = [&](const short8* kf, const short* vtb) {
        #pragma unroll
        for (int f = 0; f < 4; f++) {
            #pragma unroll
            for (int a = 0; a < 2; a++) {
                f32x4 z = {0.f, 0.f, 0.f, 0.f};
                const f32x4 sv = __builtin_amdgcn_mfma_f32_16x16x32_bf16(kf[f], qa[a], z, 0, 0, 0);
                const float p0 = __builtin_amdgcn_exp2f(fmaf(sv[0], K1, -K2));
                const float p1 = __builtin_amdgcn_exp2f(fmaf(sv[1], K1, -K2));
                const float p2 = __builtin_amdgcn_exp2f(fmaf(sv[2], K1, -K2));
                const float p3 = __builtin_amdgcn_exp2f(fmaf(sv[3], K1, -K2));
                uint2v pk = { pkbf2(p0, p1), pkbf2(p2, p3) };
                *(uint2v*)(ssw + a * 16 * 88 + f * 16) = pk;
            }
        }
        // wave-private Ss rows: in-wave DS ordering, no barrier
        #pragma unroll
        for (int kk = 0; kk < 2; kk++) {
            short8 pf[2];
            #pragma unroll
            for (int a = 0; a < 2; a++)
                pf[a] = *(const short8*)(ssr + a * 16 * 88 + kk * 32);
            #pragma unroll
            for (int nf = 0; nf < 2; nf++) {
                const short8 vf = *(const short8*)(vtb + vro[kk][nf]);
                #pragma unroll
                for (int a = 0; a < 2; a++)
                    o_acc[a][nf] = __builtin_amdgcn_mfma_f32_16x16x32_bf16(pf[a], vf, o_acc[a][nf], 0, 0, 0);
            }
            #pragma unroll
            for (int a = 0; a < 2; a++)
                o_acc[a][2] = __builtin_amdgcn_mfma_f32_16x16x32_bf16(pf[a], vf2, o_acc[a][2], 0, 0, 0);
        }
    };

    stageV(vtb0);
    loadK(kfA);

    for (int itp = 0; itp < 4; itp++) {     // 8 j-tiles (this block's half)
        __syncthreads();
        stageV(vtb1);
        loadK(kfB);
        tile(kfA, vtb0);
        __syncthreads();
        if (itp < 3) { stageV(vtb0); loadK(kfA); }
        tile(kfB, vtb1);
    }

    // ---- epilogue: bf16 partial stores, fp32 denominators (unchanged) ----
    #pragma unroll
    for (int a = 0; a < 2; a++) {
        #pragma unroll
        for (int r = 0; r < 4; r++) {
            const int il = i0 + wv * 32 + a * 16 + quad * 4 + r;
            short* po = partO + (((size_t)s * B_ + b) * L_ + il) * CIN + h * DH_;
            po[n]      = f2bf_hu(o_acc[a][0][r]);
            po[16 + n] = f2bf_hu(o_acc[a][1][r]);
        }
    }
    if (n == 0) {
        #pragma unroll
        for (int a = 0; a < 2; a++)
            #pragma unroll
            for (int r = 0; r < 4; r++) {
                const int il = i0 + wv * 32 + a * 16 + quad * 4 + r;
                partD[(((size_t)s * B_ + b) * L_ + il) * NH_ + h] = o_acc[a][2][r];
            }
    }
}

// ---------------------------------------------------------------------------
extern "C" void kernel_launch(void* const* d_in, const int* in_sizes, int n_in,
                              void* d_out, int out_size, void* d_ws, size_t ws_size,
                              hipStream_t stream) {
    const float* x      = (const float*)d_in[0];
    const float* w_qkv  = (const float*)d_in[1];
    const float* b_qkv  = (const float*)d_in[2];
    const float* w_proj = (const float*)d_in[3];
    const float* b_proj = (const float*)d_in[4];
    float* out = (float*)d_out;

    short* qkv3  = (short*)d_ws;                                // 12 MB bf16 [3][b][h][l][32]
    short* partO = qkv3 + (size_t)B_ * L_ * 768;                // 8.4 MB bf16 [2][b][l][256]
    float* partD = (float*)(partO + (size_t)2 * B_ * L_ * CIN); // 0.5 MB fp32 [2][b][l][8]
    short* w2    = (short*)(partD + (size_t)2 * B_ * L_ * NH_); // 0.5 MB bf16 weights

    wconv<<<dim3(128), 256, 0, stream>>>(w_qkv, w_proj, w2);
    qkv_gemm<<<dim3(16, 6, B_), 256, 0, stream>>>(x, w2, b_qkv, qkv3);
    attn_mfma<<<dim3(1024), 256, 0, stream>>>(qkv3, partO, partD);
    proj_gemm<<<dim3(16, 4, B_), 256, 0, stream>>>(partO, partD, w2 + (size_t)768 * 256,
                                                   b_proj, x, out);
}

// Round 7
// 107.685 us; speedup vs baseline: 1.4475x; 1.0183x over previous
//
#include <hip/hip_runtime.h>
#include <math.h>

#define B_   8
#define CIN  256
#define L_   1024
#define NH_  8
#define DH_  32

typedef __attribute__((ext_vector_type(8))) short short8;
typedef __attribute__((ext_vector_type(4))) short short4v;
typedef __attribute__((ext_vector_type(4))) float f32x4;
typedef __attribute__((ext_vector_type(16))) float f32x16;
typedef __attribute__((ext_vector_type(4))) unsigned int uint4v;

__device__ inline short f2bf_hu(float f) {       // bf16 half-up, 2 ops
    union { float f; unsigned u; } v; v.f = f;
    return (short)((v.u + 0x8000u) >> 16);
}
__device__ inline float bf2f(short s) {          // bf16 -> fp32, 1 shift
    union { unsigned u; float f; } v; v.u = ((unsigned)(unsigned short)s) << 16;
    return v.f;
}
// pack bf16(a) | bf16(b)<<16 : 2 adds + 1 v_perm (half-up, same as f2bf_hu)
__device__ inline unsigned pkbf2(float a, float b) {
    union { float f; unsigned u; } x, y; x.f = a; y.f = b;
    return __builtin_amdgcn_perm(y.u + 0x8000u, x.u + 0x8000u, 0x07060302u);
}
// async global->LDS, 16B per lane; LDS dest = wave-uniform base + lane*16
__device__ inline void glds16(const void* g, void* l) {
    __builtin_amdgcn_global_load_lds(
        (const __attribute__((address_space(1))) void*)g,
        (__attribute__((address_space(3))) void*)l, 16, 0, 0);
}

// ---------------------------------------------------------------------------
// Weight pre-convert: w_qkv + w_proj fp32 -> bf16 (byte-identical to R1).
// ---------------------------------------------------------------------------
__global__ __launch_bounds__(256) void wconv(
    const float* __restrict__ wq, const float* __restrict__ wp,
    short* __restrict__ w2)
{
    const size_t e = ((size_t)blockIdx.x * 256 + threadIdx.x) * 8;
    const float* src = (e < (size_t)768 * 256) ? wq + e : wp + (e - (size_t)768 * 256);
    const float4 a = *(const float4*)src;
    const float4 c = *(const float4*)(src + 4);
    uint4v pk = { pkbf2(a.x, a.y), pkbf2(a.z, a.w),
                  pkbf2(c.x, c.y), pkbf2(c.z, c.w) };
    *(uint4v*)(w2 + e) = pk;
}

// ---------------------------------------------------------------------------
// QKV GEMM (byte-identical to R5: head-grouped qkv3[t][b][h][l][32] output).
// ---------------------------------------------------------------------------
__global__ __launch_bounds__(256) void qkv_gemm(
    const float* __restrict__ x, const short* __restrict__ w2,
    const float* __restrict__ bias, short* __restrict__ qkv3)
{
    __shared__ __align__(16) short Xs[2][64][40];
    __shared__ __align__(16) short Wt[2][128][32];   // linear rows, swizzled content
    const int t = threadIdx.x, lane = t & 63, wv = t >> 6;
    const int n = lane & 15, quad = lane >> 4;
    const int b = blockIdx.z, o0 = blockIdx.y * 128, l0 = blockIdx.x * 64;

    float bias_r[8];
    #pragma unroll
    for (int nf = 0; nf < 8; nf++) bias_r[nf] = bias[o0 + nf * 16 + n];

    f32x4 acc[8];
    #pragma unroll
    for (int nf = 0; nf < 8; nf++) acc[nf] = (f32x4){0.f, 0.f, 0.f, 0.f};

    const int cS = t >> 3, lsS = (t & 7) * 8;       // X stage roles

    const int oA = wv * 32 + (lane >> 2);
    const int cc = (lane & 3) ^ ((oA >> 1) & 3);
    const short* wpA = w2 + (size_t)(o0 + oA) * 256 + cc * 8;
    const short* wpB = wpA + 16 * 256;
    short* const ldsW0 = &Wt[0][0][0] + wv * 1024;
    short* const ldsW1 = &Wt[1][0][0] + wv * 1024;

    auto xwrite = [&](int buf, const float4& a, const float4& c) {
        const float vals[8] = {a.x, a.y, a.z, a.w, c.x, c.y, c.z, c.w};
        #pragma unroll
        for (int k = 0; k < 8; k++) {
            const int ll = lsS + k;
            const int col = (((cS >> 3) ^ (ll & 3)) << 3) | (cS & 7);
            Xs[buf][ll][col] = f2bf_hu(vals[k]);
        }
    };

    const float* xp = &x[(((size_t)b * CIN + cS) << 10) + l0 + lsS];
    float4 xa = *(const float4*)xp, xb = *(const float4*)(xp + 4);
    glds16(wpA, ldsW0);
    glds16(wpB, ldsW0 + 512);
    xwrite(0, xa, xb);
    xp += (size_t)32 << 10;
    xa = *(const float4*)xp; xb = *(const float4*)(xp + 4);

    const int wsw = (quad ^ ((n >> 1) & 3)) * 8;
    const int arow = wv * 16 + n;
    const int xsw = (quad ^ (arow & 3)) * 8;

    #pragma unroll
    for (int it = 0; it < 8; it++) {
        const int cur = it & 1;
        __syncthreads();
        if (it < 7) {
            short* ldsn = (cur ? ldsW0 : ldsW1);
            glds16(wpA + (it + 1) * 32, ldsn);
            glds16(wpB + (it + 1) * 32, ldsn + 512);
        }
        const short8 af = *(const short8*)&Xs[cur][arow][xsw];
        #pragma unroll
        for (int nf = 0; nf < 8; nf++) {
            const short8 bf = *(const short8*)&Wt[cur][nf * 16 + n][wsw];
            acc[nf] = __builtin_amdgcn_mfma_f32_16x16x32_bf16(af, bf, acc[nf], 0, 0, 0);
        }
        if (it < 7) {
            xwrite(cur ^ 1, xa, xb);
            if (it < 6) {
                xp += (size_t)32 << 10;
                xa = *(const float4*)xp; xb = *(const float4*)(xp + 4);
            }
        }
    }

    // epilogue: head-grouped store. o = o0 + nf*16 + n;
    #pragma unroll
    for (int reg = 0; reg < 4; reg++) {
        const size_t l = l0 + wv * 16 + quad * 4 + reg;
        #pragma unroll
        for (int nf = 0; nf < 8; nf++) {
            const int o = o0 + nf * 16;
            const int tpl = o >> 8, hh = (o >> 5) & 7, dh0 = o & 31;
            short* dst = qkv3 + (((size_t)(tpl * 64 + b * 8 + hh)) << 15)
                              + l * 32 + dh0 + n;
            *dst = f2bf_hu(acc[nf][reg] + bias_r[nf]);
        }
    }
}

// ---------------------------------------------------------------------------
// Proj GEMM with fused split-j combine (byte-identical to R1).
// ---------------------------------------------------------------------------
__global__ __launch_bounds__(256) void proj_gemm(
    const short* __restrict__ partO, const float* __restrict__ partD,
    const short* __restrict__ w2, const float* __restrict__ bias,
    const float* __restrict__ resid, float* __restrict__ out)
{
    __shared__ __align__(16) short Xs[2][64][40];
    __shared__ __align__(16) short Wt[2][64][32];
    const int t = threadIdx.x, lane = t & 63, wv = t >> 6;
    const int n = lane & 15, quad = lane >> 4;
    const int b = blockIdx.z, o0 = blockIdx.y * 64, l0 = blockIdx.x * 64;

    float bias_r[4];
    #pragma unroll
    for (int reg = 0; reg < 4; reg++) bias_r[reg] = bias[o0 + wv * 16 + quad * 4 + reg];

    f32x4 acc[4];
    #pragma unroll
    for (int nf = 0; nf < 4; nf++) acc[nf] = (f32x4){0.f, 0.f, 0.f, 0.f};

    const int l = t >> 2, cs = (t & 3) * 8;
    const size_t li = ((size_t)b << 10) + l0 + l;
    const short* p0 = &partO[(0 * (size_t)B_ * L_ + li) * CIN + cs];
    const short* p1 = &partO[(1 * (size_t)B_ * L_ + li) * CIN + cs];
    const float* pd0 = &partD[(0 * (size_t)B_ * L_ + li) * NH_];
    const float* pd1 = &partD[(1 * (size_t)B_ * L_ + li) * NH_];

    const int og = wv * 16 + (lane >> 2);
    const int ccg = (lane & 3) ^ ((og >> 1) & 3);
    const short* wp = w2 + (size_t)(o0 + og) * 256 + ccg * 8;
    short* const ldsW0 = &Wt[0][0][0] + wv * 512;
    short* const ldsW1 = &Wt[1][0][0] + wv * 512;

    short8 s0, s1;
    float d0, d1;
    auto combine_write = [&](int buf) {
        const float inv = 1.f / (d0 + d1);
        float v[8];
        #pragma unroll
        for (int e = 0; e < 8; e++) v[e] = (bf2f(s0[e]) + bf2f(s1[e])) * inv;
        uint4v pw = { pkbf2(v[0], v[1]), pkbf2(v[2], v[3]),
                      pkbf2(v[4], v[5]), pkbf2(v[6], v[7]) };
        *(uint4v*)&Xs[buf][l][cs] = pw;
    };

    s0 = *(const short8*)p0; s1 = *(const short8*)p1;
    d0 = pd0[0]; d1 = pd1[0];
    glds16(wp, ldsW0);
    combine_write(0);
    p0 += 32; p1 += 32;
    s0 = *(const short8*)p0; s1 = *(const short8*)p1;
    d0 = pd0[1]; d1 = pd1[1];

    const int wsw = (quad ^ ((n >> 1) & 3)) * 8;
    #pragma unroll
    for (int it = 0; it < 8; it++) {
        const int cur = it & 1;
        __syncthreads();
        if (it < 7) glds16(wp + (it + 1) * 32, cur ? ldsW0 : ldsW1);
        const short8 af = *(const short8*)&Wt[cur][wv * 16 + n][wsw];
        #pragma unroll
        for (int nf = 0; nf < 4; nf++) {
            const short8 bf = *(const short8*)&Xs[cur][nf * 16 + n][quad * 8];
            acc[nf] = __builtin_amdgcn_mfma_f32_16x16x32_bf16(af, bf, acc[nf], 0, 0, 0);
        }
        if (it < 7) {
            combine_write(cur ^ 1);
            if (it < 6) {
                p0 += 32; p1 += 32;
                s0 = *(const short8*)p0; s1 = *(const short8*)p1;
                d0 = pd0[it + 2]; d1 = pd1[it + 2];
            }
        }
    }

    #pragma unroll
    for (int reg = 0; reg < 4; reg++) {
        const int o = o0 + wv * 16 + quad * 4 + reg;
        #pragma unroll
        for (int nf = 0; nf < 4; nf++) {
            const size_t off = (((size_t)b * CIN + o) << 10) + l0 + nf * 16 + n;
            out[off] = acc[nf][reg] + bias_r[reg] + resid[off];
        }
    }
}

// ---------------------------------------------------------------------------
// Flash attention, 32x32 MFMA + in-register P, ZERO cross-lane exchange.
// QK^T swapped: sv = mfma32(K, Q) -> lane (i=lane&31, h2=lane>>5) holds
// P[j][i] for j = 4*h2 + (reg&3) + 8*(reg>>2). The packed-pair order makes
// A-slot u of the PV fragment hold j = pi(h2,u) = 4*h2 + (u&3) + 8*(u>>2).
// Since the mfma k-slot assignment is an arbitrary bijection as long as A
// and B agree, we read V's B-fragment at pi-permuted columns (two aligned
// b64 reads per fragment) instead of exchanging P across lanes. No Ss
// buffer, no permlane, no ones-MFMA: denominator is a VALU sum + one
// shfl_xor(32) at the end. LDS = Vt only. Interface unchanged (j-split x2).
// ---------------------------------------------------------------------------
__global__ __launch_bounds__(256) void attn_mfma(
    const short* __restrict__ qkv3, short* __restrict__ partO,
    float* __restrict__ partD)
{
    __shared__ short Vt[2][32][80];                // V^T rows=dv, col j ^ msk(dv)

    const int t = threadIdx.x, lane = t & 63, wv = t >> 6;
    const int il = lane & 31, h2 = lane >> 5;
    const int id = blockIdx.x;
    const int bh = id & 63;                        // same-(b,h) -> same XCD
    const int b = bh >> 3, h = bh & 7;
    const int i0 = ((id >> 6) & 7) * 128;
    const int s  = id >> 9;                        // j-split 0/1

    const short* qbase = qkv3 + ((size_t)(b * 8 + h) << 15);
    const short* kbase = qbase + ((size_t)64 << 15);
    const short* vbase = qbase + ((size_t)128 << 15);

    // Q B-frags: B[k=h2*8+u][col=i=il]  (+16 for the dk 16..31 chain)
    const short* qp = qbase + (size_t)(i0 + wv * 32 + il) * 32 + h2 * 8;
    const short8 qa0 = *(const short8*)qp;
    const short8 qa1 = *(const short8*)(qp + 16);

    f32x16 o_acc = {0.f,0.f,0.f,0.f,0.f,0.f,0.f,0.f,
                    0.f,0.f,0.f,0.f,0.f,0.f,0.f,0.f};
    float dsum = 0.f;

    const float K1 = 0.25503510f;    // (1/sqrt(32)) * log2(e)
    const float K2 = 11.54156036f;   // 8 * log2(e)
    const int TSTRIDE = 64 * 32;     // shorts per j-tile
    const size_t soff = (size_t)s * 8 * TSTRIDE;

    // K A-frags: A[row=j=il][k=h2*8+u]  (+16 chain; +1024 for js=1)
    const short* kp = kbase + soff + (size_t)il * 32 + h2 * 8;

    const int jS = t >> 3, dsS = (t & 7) * 4;      // V stage roles
    const short* vp0 = vbase + soff + (size_t)jS * 32 + dsS;
    const short* vp1 = vp0 + 32 * 32;

    const int vmsk = ((dsS >> 2) & 7) << 3;
    const int vwo0 = dsS * 80 + (jS ^ vmsk);
    const int vwo1 = dsS * 80 + ((jS + 32) ^ vmsk);
    short* const vtb0 = &Vt[0][0][0];
    short* const vtb1 = &Vt[1][0][0];

    // V B-frag read offsets, pi-permuted: group g supplies j = js*32 + g*8
    // + 4*h2 + {0..3}; col = j ^ rmsk stays 4-aligned-consecutive because
    // rmsk has low 3 bits clear and the base is 4-aligned within an 8-group.
    const int rmsk = ((il >> 2) & 7) << 3;
    int vro2[2][4];
    #pragma unroll
    for (int js = 0; js < 2; js++)
        #pragma unroll
        for (int g = 0; g < 4; g++)
            vro2[js][g] = il * 80 + ((js * 32 + g * 8 + 4 * h2) ^ rmsk);

    short8 kfA[4], kfB[4];

    auto stageV = [&](short* vtb) {
        const short4v a = *(const short4v*)vp0; vp0 += TSTRIDE;
        const short4v c = *(const short4v*)vp1; vp1 += TSTRIDE;
        #pragma unroll
        for (int u = 0; u < 4; u++) {
            vtb[vwo0 + u * 80] = a[u];
            vtb[vwo1 + u * 80] = c[u];
        }
    };
    auto loadK = [&](short8* kf) {
        kf[0] = *(const short8*)kp;                 // js=0, dk 0-15 half
        kf[1] = *(const short8*)(kp + 16);          // js=0, dk 16-31 half
        kf[2] = *(const short8*)(kp + 1024);        // js=1 (+32 j rows)
        kf[3] = *(const short8*)(kp + 1024 + 16);
        kp += TSTRIDE;
    };
    auto tile = [&](const short8* kf, const short* vtb) {
        #pragma unroll
        for (int js = 0; js < 2; js++) {
            const f32x16 Z = {0.f,0.f,0.f,0.f,0.f,0.f,0.f,0.f,
                              0.f,0.f,0.f,0.f,0.f,0.f,0.f,0.f};
            f32x16 sv = __builtin_amdgcn_mfma_f32_32x32x16_bf16(kf[js*2],   qa0, Z,  0, 0, 0);
            sv        = __builtin_amdgcn_mfma_f32_32x32x16_bf16(kf[js*2+1], qa1, sv, 0, 0, 0);
            // softmax numerator (bounded, no max-pass) + denominator partial
            unsigned c[8];
            #pragma unroll
            for (int pi = 0; pi < 8; pi++) {
                const float pl = __builtin_amdgcn_exp2f(fmaf(sv[2*pi],   K1, -K2));
                const float ph = __builtin_amdgcn_exp2f(fmaf(sv[2*pi+1], K1, -K2));
                dsum += pl; dsum += ph;
                c[pi] = pkbf2(pl, ph);
            }
            // A-frags ARE the natural packing (slot u -> j = pi(h2,u))
            union { unsigned u[4]; short8 s8; } pa0, pa1;
            pa0.u[0] = c[0]; pa0.u[1] = c[1]; pa0.u[2] = c[2]; pa0.u[3] = c[3];
            pa1.u[0] = c[4]; pa1.u[1] = c[5]; pa1.u[2] = c[6]; pa1.u[3] = c[7];
            // B-frags: pi-permuted V columns, two b64 reads each
            union { short4v h4[2]; short8 s8; } vf0, vf1;
            vf0.h4[0] = *(const short4v*)(vtb + vro2[js][0]);
            vf0.h4[1] = *(const short4v*)(vtb + vro2[js][1]);
            o_acc = __builtin_amdgcn_mfma_f32_32x32x16_bf16(pa0.s8, vf0.s8, o_acc, 0, 0, 0);
            vf1.h4[0] = *(const short4v*)(vtb + vro2[js][2]);
            vf1.h4[1] = *(const short4v*)(vtb + vro2[js][3]);
            o_acc = __builtin_amdgcn_mfma_f32_32x32x16_bf16(pa1.s8, vf1.s8, o_acc, 0, 0, 0);
        }
    };

    stageV(vtb0);
    loadK(kfA);

    for (int itp = 0; itp < 4; itp++) {     // 8 j-tiles (this block's half)
        __syncthreads();
        stageV(vtb1);
        loadK(kfB);
        tile(kfA, vtb0);
        __syncthreads();
        if (itp < 3) { stageV(vtb0); loadK(kfA); }
        tile(kfB, vtb1);
    }

    // ---- epilogue: bf16 partial stores + fp32 denominators ----
    const float dtot = dsum + __shfl_xor(dsum, 32);
    #pragma unroll
    for (int r = 0; r < 16; r++) {
        const int irow = (r & 3) + 8 * (r >> 2) + 4 * h2;
        const int ig = i0 + wv * 32 + irow;
        partO[(((size_t)s * B_ + b) * L_ + ig) * CIN + h * DH_ + il]
            = f2bf_hu(o_acc[r]);
    }
    if (lane < 32)
        partD[(((size_t)s * B_ + b) * L_ + (i0 + wv * 32 + il)) * NH_ + h] = dtot;
}

// ---------------------------------------------------------------------------
extern "C" void kernel_launch(void* const* d_in, const int* in_sizes, int n_in,
                              void* d_out, int out_size, void* d_ws, size_t ws_size,
                              hipStream_t stream) {
    const float* x      = (const float*)d_in[0];
    const float* w_qkv  = (const float*)d_in[1];
    const float* b_qkv  = (const float*)d_in[2];
    const float* w_proj = (const float*)d_in[3];
    const float* b_proj = (const float*)d_in[4];
    float* out = (float*)d_out;

    short* qkv3  = (short*)d_ws;                                // 12 MB bf16 [3][b][h][l][32]
    short* partO = qkv3 + (size_t)B_ * L_ * 768;                // 8.4 MB bf16 [2][b][l][256]
    float* partD = (float*)(partO + (size_t)2 * B_ * L_ * CIN); // 0.5 MB fp32 [2][b][l][8]
    short* w2    = (short*)(partD + (size_t)2 * B_ * L_ * NH_); // 0.5 MB bf16 weights

    wconv<<<dim3(128), 256, 0, stream>>>(w_qkv, w_proj, w2);
    qkv_gemm<<<dim3(16, 6, B_), 256, 0, stream>>>(x, w2, b_qkv, qkv3);
    attn_mfma<<<dim3(1024), 256, 0, stream>>>(qkv3, partO, partD);
    proj_gemm<<<dim3(16, 4, B_), 256, 0, stream>>>(partO, partD, w2 + (size_t)768 * 256,
                                                   b_proj, x, out);
}

// Round 8
// 105.973 us; speedup vs baseline: 1.4709x; 1.0162x over previous
//
#include <hip/hip_runtime.h>
#include <math.h>

#define B_   8
#define CIN  256
#define L_   1024
#define NH_  8
#define DH_  32

typedef __attribute__((ext_vector_type(8))) short short8;
typedef __attribute__((ext_vector_type(4))) short short4v;
typedef __attribute__((ext_vector_type(4))) float f32x4;
typedef __attribute__((ext_vector_type(16))) float f32x16;
typedef __attribute__((ext_vector_type(4))) unsigned int uint4v;

__device__ inline short f2bf_hu(float f) {       // bf16 half-up, 2 ops
    union { float f; unsigned u; } v; v.f = f;
    return (short)((v.u + 0x8000u) >> 16);
}
__device__ inline float bf2f(short s) {          // bf16 -> fp32, 1 shift
    union { unsigned u; float f; } v; v.u = ((unsigned)(unsigned short)s) << 16;
    return v.f;
}
// pack bf16(a) | bf16(b)<<16 : 2 adds + 1 v_perm (half-up, same as f2bf_hu)
__device__ inline unsigned pkbf2(float a, float b) {
    union { float f; unsigned u; } x, y; x.f = a; y.f = b;
    return __builtin_amdgcn_perm(y.u + 0x8000u, x.u + 0x8000u, 0x07060302u);
}

// ---------------------------------------------------------------------------
// QKV GEMM — R5/R7 structure, but weight conversion is INLINE (wconv kernel
// deleted). Thread t stages W row o0 + (t>>1), half (t&1): 16 fp32 -> 16 bf16
// written at the XOR-swizzled chunk positions ((j)^((o>>1)&3)), identical to
// the glds-source pre-swizzle, so the MFMA read side is unchanged. W regs
// prefetched one K-step ahead, mirroring the X pipeline.
// Output: head-grouped qkv3[t][b][h][l][32] (byte-identical values to R7).
// ---------------------------------------------------------------------------
__global__ __launch_bounds__(256) void qkv_gemm(
    const float* __restrict__ x, const float* __restrict__ wq,
    const float* __restrict__ bias, short* __restrict__ qkv3)
{
    __shared__ __align__(16) short Xs[2][64][40];
    __shared__ __align__(16) short Wt[2][128][32];   // linear rows, swizzled content
    const int t = threadIdx.x, lane = t & 63, wv = t >> 6;
    const int n = lane & 15, quad = lane >> 4;
    const int b = blockIdx.z, o0 = blockIdx.y * 128, l0 = blockIdx.x * 64;

    float bias_r[8];
    #pragma unroll
    for (int nf = 0; nf < 8; nf++) bias_r[nf] = bias[o0 + nf * 16 + n];

    f32x4 acc[8];
    #pragma unroll
    for (int nf = 0; nf < 8; nf++) acc[nf] = (f32x4){0.f, 0.f, 0.f, 0.f};

    const int cS = t >> 3, lsS = (t & 7) * 8;       // X stage roles

    // W stage roles: row ow, 16-col half hw
    const int ow = t >> 1, hw = t & 1;
    const float* wp = wq + (size_t)(o0 + ow) * 256 + hw * 16;
    const int wssw = (ow >> 1) & 3;                 // chunk swizzle key
    float4 wr0, wr1, wr2, wr3;
    auto loadW = [&]() {
        wr0 = ((const float4*)wp)[0]; wr1 = ((const float4*)wp)[1];
        wr2 = ((const float4*)wp)[2]; wr3 = ((const float4*)wp)[3];
        wp += 32;
    };
    auto wwrite = [&](int buf) {
        uint4v pa = { pkbf2(wr0.x, wr0.y), pkbf2(wr0.z, wr0.w),
                      pkbf2(wr1.x, wr1.y), pkbf2(wr1.z, wr1.w) };
        uint4v pb = { pkbf2(wr2.x, wr2.y), pkbf2(wr2.z, wr2.w),
                      pkbf2(wr3.x, wr3.y), pkbf2(wr3.z, wr3.w) };
        *(uint4v*)&Wt[buf][ow][((hw * 2)     ^ wssw) * 8] = pa;
        *(uint4v*)&Wt[buf][ow][((hw * 2 + 1) ^ wssw) * 8] = pb;
    };

    auto xwrite = [&](int buf, const float4& a, const float4& c) {
        const float vals[8] = {a.x, a.y, a.z, a.w, c.x, c.y, c.z, c.w};
        #pragma unroll
        for (int k = 0; k < 8; k++) {
            const int ll = lsS + k;
            const int col = (((cS >> 3) ^ (ll & 3)) << 3) | (cS & 7);
            Xs[buf][ll][col] = f2bf_hu(vals[k]);
        }
    };

    // prologue: stage step 0, prefetch step 1 into regs
    const float* xp = &x[(((size_t)b * CIN + cS) << 10) + l0 + lsS];
    float4 xa = *(const float4*)xp, xb = *(const float4*)(xp + 4);
    loadW();
    xwrite(0, xa, xb);
    wwrite(0);
    xp += (size_t)32 << 10;
    xa = *(const float4*)xp; xb = *(const float4*)(xp + 4);
    loadW();

    const int wsw = (quad ^ ((n >> 1) & 3)) * 8;
    const int arow = wv * 16 + n;
    const int xsw = (quad ^ (arow & 3)) * 8;

    #pragma unroll
    for (int it = 0; it < 8; it++) {
        const int cur = it & 1;
        __syncthreads();
        const short8 af = *(const short8*)&Xs[cur][arow][xsw];
        #pragma unroll
        for (int nf = 0; nf < 8; nf++) {
            const short8 bf = *(const short8*)&Wt[cur][nf * 16 + n][wsw];
            acc[nf] = __builtin_amdgcn_mfma_f32_16x16x32_bf16(af, bf, acc[nf], 0, 0, 0);
        }
        if (it < 7) {
            xwrite(cur ^ 1, xa, xb);
            wwrite(cur ^ 1);
            if (it < 6) {
                xp += (size_t)32 << 10;
                xa = *(const float4*)xp; xb = *(const float4*)(xp + 4);
                loadW();
            }
        }
    }

    // epilogue: head-grouped store. o = o0 + nf*16 + n;
    #pragma unroll
    for (int reg = 0; reg < 4; reg++) {
        const size_t l = l0 + wv * 16 + quad * 4 + reg;
        #pragma unroll
        for (int nf = 0; nf < 8; nf++) {
            const int o = o0 + nf * 16;
            const int tpl = o >> 8, hh = (o >> 5) & 7, dh0 = o & 31;
            short* dst = qkv3 + (((size_t)(tpl * 64 + b * 8 + hh)) << 15)
                              + l * 32 + dh0 + n;
            *dst = f2bf_hu(acc[nf][reg] + bias_r[nf]);
        }
    }
}

// ---------------------------------------------------------------------------
// Proj GEMM — R1 structure with INLINE weight conversion (fp32 w_proj input).
// Thread t stages W row o0 + (t>>2), chunk (t&3): 8 fp32 -> 8 bf16 at the
// swizzled chunk position; prefetched one K-step ahead like the combine path.
// ---------------------------------------------------------------------------
__global__ __launch_bounds__(256) void proj_gemm(
    const short* __restrict__ partO, const float* __restrict__ partD,
    const float* __restrict__ wq, const float* __restrict__ bias,
    const float* __restrict__ resid, float* __restrict__ out)
{
    __shared__ __align__(16) short Xs[2][64][40];
    __shared__ __align__(16) short Wt[2][64][32];
    const int t = threadIdx.x, lane = t & 63, wv = t >> 6;
    const int n = lane & 15, quad = lane >> 4;
    const int b = blockIdx.z, o0 = blockIdx.y * 64, l0 = blockIdx.x * 64;

    float bias_r[4];
    #pragma unroll
    for (int reg = 0; reg < 4; reg++) bias_r[reg] = bias[o0 + wv * 16 + quad * 4 + reg];

    f32x4 acc[4];
    #pragma unroll
    for (int nf = 0; nf < 4; nf++) acc[nf] = (f32x4){0.f, 0.f, 0.f, 0.f};

    // combine-stage roles: one l-row, 8 c's per thread
    const int l = t >> 2, cs = (t & 3) * 8;
    const size_t li = ((size_t)b << 10) + l0 + l;
    const short* p0 = &partO[(0 * (size_t)B_ * L_ + li) * CIN + cs];
    const short* p1 = &partO[(1 * (size_t)B_ * L_ + li) * CIN + cs];
    const float* pd0 = &partD[(0 * (size_t)B_ * L_ + li) * NH_];
    const float* pd1 = &partD[(1 * (size_t)B_ * L_ + li) * NH_];

    // W stage roles: row ow, chunk cw
    const int ow = t >> 2, cw = t & 3;
    const float* wp = wq + (size_t)(o0 + ow) * 256 + cw * 8;
    const int wpos = (cw ^ ((ow >> 1) & 3)) * 8;
    float4 wa, wb;
    auto loadW = [&]() {
        wa = ((const float4*)wp)[0]; wb = ((const float4*)wp)[1];
        wp += 32;
    };
    auto wwrite = [&](int buf) {
        uint4v pw = { pkbf2(wa.x, wa.y), pkbf2(wa.z, wa.w),
                      pkbf2(wb.x, wb.y), pkbf2(wb.z, wb.w) };
        *(uint4v*)&Wt[buf][ow][wpos] = pw;
    };

    short8 s0, s1;
    float d0, d1;
    auto combine_write = [&](int buf) {
        const float inv = 1.f / (d0 + d1);
        float v[8];
        #pragma unroll
        for (int e = 0; e < 8; e++) v[e] = (bf2f(s0[e]) + bf2f(s1[e])) * inv;
        uint4v pw = { pkbf2(v[0], v[1]), pkbf2(v[2], v[3]),
                      pkbf2(v[4], v[5]), pkbf2(v[6], v[7]) };
        *(uint4v*)&Xs[buf][l][cs] = pw;
    };

    // prologue
    s0 = *(const short8*)p0; s1 = *(const short8*)p1;
    d0 = pd0[0]; d1 = pd1[0];
    loadW();
    combine_write(0);
    wwrite(0);
    p0 += 32; p1 += 32;
    s0 = *(const short8*)p0; s1 = *(const short8*)p1;
    d0 = pd0[1]; d1 = pd1[1];
    loadW();

    const int wsw = (quad ^ ((n >> 1) & 3)) * 8;
    #pragma unroll
    for (int it = 0; it < 8; it++) {
        const int cur = it & 1;
        __syncthreads();
        const short8 af = *(const short8*)&Wt[cur][wv * 16 + n][wsw];
        #pragma unroll
        for (int nf = 0; nf < 4; nf++) {
            const short8 bf = *(const short8*)&Xs[cur][nf * 16 + n][quad * 8];
            acc[nf] = __builtin_amdgcn_mfma_f32_16x16x32_bf16(af, bf, acc[nf], 0, 0, 0);
        }
        if (it < 7) {
            combine_write(cur ^ 1);
            wwrite(cur ^ 1);
            if (it < 6) {
                p0 += 32; p1 += 32;
                s0 = *(const short8*)p0; s1 = *(const short8*)p1;
                d0 = pd0[it + 2]; d1 = pd1[it + 2];
                loadW();
            }
        }
    }

    #pragma unroll
    for (int reg = 0; reg < 4; reg++) {
        const int o = o0 + wv * 16 + quad * 4 + reg;
        #pragma unroll
        for (int nf = 0; nf < 4; nf++) {
            const size_t off = (((size_t)b * CIN + o) << 10) + l0 + nf * 16 + n;
            out[off] = acc[nf][reg] + bias_r[reg] + resid[off];
        }
    }
}

// ---------------------------------------------------------------------------
// Flash attention (byte-identical to R7: 32x32 MFMA, in-register P with
// pi-permuted V columns, zero cross-lane exchange, j-split x2).
// ---------------------------------------------------------------------------
__global__ __launch_bounds__(256) void attn_mfma(
    const short* __restrict__ qkv3, short* __restrict__ partO,
    float* __restrict__ partD)
{
    __shared__ short Vt[2][32][80];                // V^T rows=dv, col j ^ msk(dv)

    const int t = threadIdx.x, lane = t & 63, wv = t >> 6;
    const int il = lane & 31, h2 = lane >> 5;
    const int id = blockIdx.x;
    const int bh = id & 63;                        // same-(b,h) -> same XCD
    const int b = bh >> 3, h = bh & 7;
    const int i0 = ((id >> 6) & 7) * 128;
    const int s  = id >> 9;                        // j-split 0/1

    const short* qbase = qkv3 + ((size_t)(b * 8 + h) << 15);
    const short* kbase = qbase + ((size_t)64 << 15);
    const short* vbase = qbase + ((size_t)128 << 15);

    // Q B-frags: B[k=h2*8+u][col=i=il]  (+16 for the dk 16..31 chain)
    const short* qp = qbase + (size_t)(i0 + wv * 32 + il) * 32 + h2 * 8;
    const short8 qa0 = *(const short8*)qp;
    const short8 qa1 = *(const short8*)(qp + 16);

    f32x16 o_acc = {0.f,0.f,0.f,0.f,0.f,0.f,0.f,0.f,
                    0.f,0.f,0.f,0.f,0.f,0.f,0.f,0.f};
    float dsum = 0.f;

    const float K1 = 0.25503510f;    // (1/sqrt(32)) * log2(e)
    const float K2 = 11.54156036f;   // 8 * log2(e)
    const int TSTRIDE = 64 * 32;     // shorts per j-tile
    const size_t soff = (size_t)s * 8 * TSTRIDE;

    // K A-frags: A[row=j=il][k=h2*8+u]  (+16 chain; +1024 for js=1)
    const short* kp = kbase + soff + (size_t)il * 32 + h2 * 8;

    const int jS = t >> 3, dsS = (t & 7) * 4;      // V stage roles
    const short* vp0 = vbase + soff + (size_t)jS * 32 + dsS;
    const short* vp1 = vp0 + 32 * 32;

    const int vmsk = ((dsS >> 2) & 7) << 3;
    const int vwo0 = dsS * 80 + (jS ^ vmsk);
    const int vwo1 = dsS * 80 + ((jS + 32) ^ vmsk);
    short* const vtb0 = &Vt[0][0][0];
    short* const vtb1 = &Vt[1][0][0];

    // V B-frag read offsets, pi-permuted: group g supplies j = js*32 + g*8
    // + 4*h2 + {0..3}; col = j ^ rmsk stays 4-aligned-consecutive.
    const int rmsk = ((il >> 2) & 7) << 3;
    int vro2[2][4];
    #pragma unroll
    for (int js = 0; js < 2; js++)
        #pragma unroll
        for (int g = 0; g < 4; g++)
            vro2[js][g] = il * 80 + ((js * 32 + g * 8 + 4 * h2) ^ rmsk);

    short8 kfA[4], kfB[4];

    auto stageV = [&](short* vtb) {
        const short4v a = *(const short4v*)vp0; vp0 += TSTRIDE;
        const short4v c = *(const short4v*)vp1; vp1 += TSTRIDE;
        #pragma unroll
        for (int u = 0; u < 4; u++) {
            vtb[vwo0 + u * 80] = a[u];
            vtb[vwo1 + u * 80] = c[u];
        }
    };
    auto loadK = [&](short8* kf) {
        kf[0] = *(const short8*)kp;                 // js=0, dk 0-15 half
        kf[1] = *(const short8*)(kp + 16);          // js=0, dk 16-31 half
        kf[2] = *(const short8*)(kp + 1024);        // js=1 (+32 j rows)
        kf[3] = *(const short8*)(kp + 1024 + 16);
        kp += TSTRIDE;
    };
    auto tile = [&](const short8* kf, const short* vtb) {
        #pragma unroll
        for (int js = 0; js < 2; js++) {
            const f32x16 Z = {0.f,0.f,0.f,0.f,0.f,0.f,0.f,0.f,
                              0.f,0.f,0.f,0.f,0.f,0.f,0.f,0.f};
            f32x16 sv = __builtin_amdgcn_mfma_f32_32x32x16_bf16(kf[js*2],   qa0, Z,  0, 0, 0);
            sv        = __builtin_amdgcn_mfma_f32_32x32x16_bf16(kf[js*2+1], qa1, sv, 0, 0, 0);
            // softmax numerator (bounded, no max-pass) + denominator partial
            unsigned c[8];
            #pragma unroll
            for (int pi = 0; pi < 8; pi++) {
                const float pl = __builtin_amdgcn_exp2f(fmaf(sv[2*pi],   K1, -K2));
                const float ph = __builtin_amdgcn_exp2f(fmaf(sv[2*pi+1], K1, -K2));
                dsum += pl; dsum += ph;
                c[pi] = pkbf2(pl, ph);
            }
            // A-frags ARE the natural packing (slot u -> j = pi(h2,u))
            union { unsigned u[4]; short8 s8; } pa0, pa1;
            pa0.u[0] = c[0]; pa0.u[1] = c[1]; pa0.u[2] = c[2]; pa0.u[3] = c[3];
            pa1.u[0] = c[4]; pa1.u[1] = c[5]; pa1.u[2] = c[6]; pa1.u[3] = c[7];
            // B-frags: pi-permuted V columns, two b64 reads each
            union { short4v h4[2]; short8 s8; } vf0, vf1;
            vf0.h4[0] = *(const short4v*)(vtb + vro2[js][0]);
            vf0.h4[1] = *(const short4v*)(vtb + vro2[js][1]);
            o_acc = __builtin_amdgcn_mfma_f32_32x32x16_bf16(pa0.s8, vf0.s8, o_acc, 0, 0, 0);
            vf1.h4[0] = *(const short4v*)(vtb + vro2[js][2]);
            vf1.h4[1] = *(const short4v*)(vtb + vro2[js][3]);
            o_acc = __builtin_amdgcn_mfma_f32_32x32x16_bf16(pa1.s8, vf1.s8, o_acc, 0, 0, 0);
        }
    };

    stageV(vtb0);
    loadK(kfA);

    for (int itp = 0; itp < 4; itp++) {     // 8 j-tiles (this block's half)
        __syncthreads();
        stageV(vtb1);
        loadK(kfB);
        tile(kfA, vtb0);
        __syncthreads();
        if (itp < 3) { stageV(vtb0); loadK(kfA); }
        tile(kfB, vtb1);
    }

    // ---- epilogue: bf16 partial stores + fp32 denominators ----
    const float dtot = dsum + __shfl_xor(dsum, 32);
    #pragma unroll
    for (int r = 0; r < 16; r++) {
        const int irow = (r & 3) + 8 * (r >> 2) + 4 * h2;
        const int ig = i0 + wv * 32 + irow;
        partO[(((size_t)s * B_ + b) * L_ + ig) * CIN + h * DH_ + il]
            = f2bf_hu(o_acc[r]);
    }
    if (lane < 32)
        partD[(((size_t)s * B_ + b) * L_ + (i0 + wv * 32 + il)) * NH_ + h] = dtot;
}

// ---------------------------------------------------------------------------
extern "C" void kernel_launch(void* const* d_in, const int* in_sizes, int n_in,
                              void* d_out, int out_size, void* d_ws, size_t ws_size,
                              hipStream_t stream) {
    const float* x      = (const float*)d_in[0];
    const float* w_qkv  = (const float*)d_in[1];
    const float* b_qkv  = (const float*)d_in[2];
    const float* w_proj = (const float*)d_in[3];
    const float* b_proj = (const float*)d_in[4];
    float* out = (float*)d_out;

    short* qkv3  = (short*)d_ws;                                // 12 MB bf16 [3][b][h][l][32]
    short* partO = qkv3 + (size_t)B_ * L_ * 768;                // 8.4 MB bf16 [2][b][l][256]
    float* partD = (float*)(partO + (size_t)2 * B_ * L_ * CIN); // 0.5 MB fp32 [2][b][l][8]

    qkv_gemm<<<dim3(16, 6, B_), 256, 0, stream>>>(x, w_qkv, b_qkv, qkv3);
    attn_mfma<<<dim3(1024), 256, 0, stream>>>(qkv3, partO, partD);
    proj_gemm<<<dim3(16, 4, B_), 256, 0, stream>>>(partO, partD, w_proj,
                                                   b_proj, x, out);
}